// Round 3
// baseline (190.757 us; speedup 1.0000x reference)
//
#include <hip/hip_runtime.h>
#include <stdint.h>

// Problem: cosine-similarity relations.
//   support: (2,5,1024,128) fp32 -> 10240 rows; query: (2,4,1024,128) -> 8192 rows
//   out: (2,4,5,1024,1024) fp32 = 167.8 MB  -> write-BW-bound (~27 us floor)
// R2 -> R3: drop LDS staging entirely. K=128 means the MFMA A/B fragment of
// each lane is a contiguous 16 B chunk of a bf16 row -> load fragments
// straight global->VGPR with dwordx4. Inputs are 4.7 MB (L2/LLC-resident);
// the 2x read amplification vs LDS sharing costs ~327 MB of L2 traffic
// (~10 us at 34.5 TB/s), hidden under the 27 us HBM write stream. Removes
// LDS bank conflicts, the vmcnt(0)+s_barrier drain, and the LDS occupancy cap.

#define S_ROWS 10240
#define Q_ROWS 8192

typedef __attribute__((ext_vector_type(8))) short short8;   // 8 bf16 (4 VGPRs)
typedef __attribute__((ext_vector_type(4))) float floatx4;  // 16x16 MFMA acc

__device__ static inline unsigned short f32_to_bf16_rne(float f) {
    union { float f; uint32_t u; } c; c.f = f;
    uint32_t u = c.u;
    uint32_t r = u + 0x7FFFu + ((u >> 16) & 1u);   // round-to-nearest-even
    return (unsigned short)(r >> 16);
}

// ---------------- Kernel 1: L2-normalize rows of 128, cast to bf16 ----------
__global__ __launch_bounds__(256) void norm_cast_kernel(
    const float* __restrict__ support, const float* __restrict__ query,
    unsigned short* __restrict__ sn, unsigned short* __restrict__ qn)
{
    int wave = blockIdx.x * 4 + (threadIdx.x >> 6);
    int lane = threadIdx.x & 63;

    const float* src;
    unsigned short* dst;
    if (wave < S_ROWS) {
        src = support + (size_t)wave * 128;
        dst = sn + (size_t)wave * 128;
    } else {
        int r = wave - S_ROWS;
        src = query + (size_t)r * 128;
        dst = qn + (size_t)r * 128;
    }

    float2 v = ((const float2*)src)[lane];
    float s = v.x * v.x + v.y * v.y;
    #pragma unroll
    for (int off = 32; off > 0; off >>= 1) s += __shfl_xor(s, off, 64);
    float inv = 1.0f / fmaxf(sqrtf(s), 1e-12f);

    unsigned short lo = f32_to_bf16_rne(v.x * inv);
    unsigned short hi = f32_to_bf16_rne(v.y * inv);
    ((uint32_t*)dst)[lane] = ((uint32_t)hi << 16) | (uint32_t)lo;
}

// ---------------- Kernel 2: batched C = Qn * Sn^T via bf16 MFMA -------------
// Block = 256 threads (4 waves), 128x128 output tile, 64x64 per wave.
// No LDS: fragments loaded directly from global (L2-hot bf16 rows).
// MFMA 16x16x32 operand layout: lane (quad,ml) holds X[row=ml][k=quad*8 + j],
// j=0..7 -> one 16 B dwordx4 at rowptr + quad*16 B + kb*64 B.
__global__ __launch_bounds__(256) void gemm_bt_kernel(
    const unsigned short* __restrict__ qn, const unsigned short* __restrict__ sn,
    float* __restrict__ out)
{
    const int tid  = threadIdx.x;
    const int wave = tid >> 6;
    const int lane = tid & 63;

    const int tn = blockIdx.x & 7;
    const int tm = blockIdx.x >> 3;
    const int y   = blockIdx.y;          // 0..39 -> (b,i,j)
    const int b   = y / 20;
    const int rem = y % 20;
    const int i   = rem / 5;
    const int j   = rem % 5;

    const int wm   = (wave >> 1) * 64;   // wave's 64x64 sub-tile of the 128x128
    const int wn   = (wave & 1) * 64;
    const int ml   = lane & 15;
    const int quad = lane >> 4;

    // Per-lane fragment base pointers (ushort units; quad*8 = 16 B k-chunk).
    const unsigned short* pA = qn
        + ((size_t)(b * 4 + i) * 1024 + tm * 128 + wm + ml) * 128 + quad * 8;
    const unsigned short* pB = sn
        + ((size_t)(b * 5 + j) * 1024 + tn * 128 + wn + ml) * 128 + quad * 8;

    floatx4 acc[4][4] = {};

    #pragma unroll
    for (int kb = 0; kb < 4; ++kb) {
        short8 a[4], bf[4];
        #pragma unroll
        for (int mi = 0; mi < 4; ++mi)
            a[mi] = *(const short8*)&pA[mi * 16 * 128 + kb * 32];
        #pragma unroll
        for (int ni = 0; ni < 4; ++ni)
            bf[ni] = *(const short8*)&pB[ni * 16 * 128 + kb * 32];
        #pragma unroll
        for (int mi = 0; mi < 4; ++mi)
            #pragma unroll
            for (int ni = 0; ni < 4; ++ni)
                acc[mi][ni] = __builtin_amdgcn_mfma_f32_16x16x32_bf16(
                    a[mi], bf[ni], acc[mi][ni], 0, 0, 0);
    }

    // Epilogue: C/D layout col=lane&15, row=quad*4+reg (m89/m91-verified).
    // Per store inst, each quad's 16 lanes cover one aligned 64 B line.
    float* gC = out + ((size_t)((b * 4 + i) * 5 + j) << 20)
                    + (size_t)(tm * 128) * 1024 + tn * 128;
    #pragma unroll
    for (int mi = 0; mi < 4; ++mi) {
        #pragma unroll
        for (int r = 0; r < 4; ++r) {
            const int row = wm + mi * 16 + quad * 4 + r;
            float* rowp = gC + (size_t)row * 1024 + wn + ml;
            #pragma unroll
            for (int ni = 0; ni < 4; ++ni)
                rowp[ni * 16] = acc[mi][ni][r];
        }
    }
}

extern "C" void kernel_launch(void* const* d_in, const int* in_sizes, int n_in,
                              void* d_out, int out_size, void* d_ws, size_t ws_size,
                              hipStream_t stream) {
    const float* support = (const float*)d_in[0];   // (2,5,1024,128)
    const float* query   = (const float*)d_in[1];   // (2,4,1024,128)
    unsigned short* sn = (unsigned short*)d_ws;             // 10240*128 bf16
    unsigned short* qn = sn + (size_t)S_ROWS * 128;         //  8192*128 bf16
    float* out = (float*)d_out;

    norm_cast_kernel<<<dim3((S_ROWS + Q_ROWS) / 4), dim3(256), 0, stream>>>(
        support, query, sn, qn);
    gemm_bt_kernel<<<dim3(64, 40), dim3(256), 0, stream>>>(qn, sn, out);
}